// Round 3
// baseline (515.417 us; speedup 1.0000x reference)
//
#include <hip/hip_runtime.h>

typedef unsigned short u16;
typedef unsigned int u32;
typedef __attribute__((ext_vector_type(8))) short bf16x8;
typedef __attribute__((ext_vector_type(4))) float f32x4;

namespace {

constexpr int S = 1024, D = 1024, H = 16, DK = 64;
constexpr float NEGF = -1e30f;

__device__ __forceinline__ u16 f2bf(float f){
  u32 u = __builtin_bit_cast(u32, f);
  u32 r = (u + 0x7fffu + ((u >> 16) & 1u)) >> 16;
  return (u16)r;
}
__device__ __forceinline__ float bf2f(u16 h){
  u32 u = ((u32)h) << 16;
  return __builtin_bit_cast(float, u);
}
__device__ __forceinline__ u32 pack2(float a, float b){
  return (u32)f2bf(a) | ((u32)f2bf(b) << 16);
}
__device__ __forceinline__ void glds16(const u16* g, u16* l){
  __builtin_amdgcn_global_load_lds(
      (const __attribute__((address_space(1))) u32*)g,
      (__attribute__((address_space(3))) u32*)l, 16, 0, 0);
}

// ---------------------------------------------------------------- weight f32->bf16
struct CvtArgs { const float* src[10]; u16* dst[10]; };
__global__ __launch_bounds__(256) void cvt_kernel(CvtArgs a){
  int m = blockIdx.y;
  const float* s = a.src[m];
  u16* d = a.dst[m];
  int i = (blockIdx.x * 256 + threadIdx.x) * 8;
  float4 v0 = *(const float4*)(s + i), v1 = *(const float4*)(s + i + 4);
  u32 p[4] = { pack2(v0.x,v0.y), pack2(v0.z,v0.w), pack2(v1.x,v1.y), pack2(v1.z,v1.w) };
  *(uint4*)(d + i) = *(uint4*)p;
}

// ---------------------------------------------------------------- seg scan
__global__ void seg_kernel(const int* __restrict__ ids, int* __restrict__ segd){
  __shared__ int sc[1024];
  int b = blockIdx.x, t = threadIdx.x;
  int id = ids[b*S + t];
  sc[t] = (id == 1) ? 1 : 0;
  __syncthreads();
  for(int off = 1; off < 1024; off <<= 1){
    int add = (t >= off) ? sc[t - off] : 0;
    __syncthreads();
    sc[t] += add;
    __syncthreads();
  }
  int seg = sc[t];
  segd[b*S + t] = (seg << 2) | ((id == 2) ? 2 : 0) | ((id != 0) ? 1 : 0);
}

// ---------------------------------------------------------------- layernorm
__global__ __launch_bounds__(256) void ln_kernel(const float* __restrict__ x,
    const float* __restrict__ w, const float* __restrict__ bias, u16* __restrict__ out){
  int row = blockIdx.x, t = threadIdx.x;
  float4 v = ((const float4*)(x + (size_t)row*D))[t];
  float s = v.x + v.y + v.z + v.w;
  float q = v.x*v.x + v.y*v.y + v.z*v.z + v.w*v.w;
  for(int off = 32; off >= 1; off >>= 1){ s += __shfl_down(s, off); q += __shfl_down(q, off); }
  __shared__ float ls[4], lq[4];
  int wv = t >> 6, ln = t & 63;
  if(ln == 0){ ls[wv] = s; lq[wv] = q; }
  __syncthreads();
  s = ls[0] + ls[1] + ls[2] + ls[3];
  q = lq[0] + lq[1] + lq[2] + lq[3];
  float mean = s * (1.f/D);
  float var  = q * (1.f/D) - mean*mean;
  float rs = rsqrtf(var + 1e-5f);
  float4 wv4 = ((const float4*)w)[t];
  float4 bv4 = ((const float4*)bias)[t];
  ushort4 o;
  o.x = f2bf((v.x-mean)*rs*wv4.x + bv4.x);
  o.y = f2bf((v.y-mean)*rs*wv4.y + bv4.y);
  o.z = f2bf((v.z-mean)*rs*wv4.z + bv4.z);
  o.w = f2bf((v.w-mean)*rs*wv4.w + bv4.w);
  *(ushort4*)(out + (size_t)row*D + t*4) = o;
}

// ---------------------------------------------------------------- head proj -> transposed [b,h,s]
template<bool DUAL>
__global__ __launch_bounds__(256) void headproj_kernel(const u16* __restrict__ xln,
    const float* __restrict__ wg, const float* __restrict__ bg, float* __restrict__ outg,
    const float* __restrict__ wa, float* __restrict__ outa){
  __shared__ u16 xrow[D];
  int row = blockIdx.x, t = threadIdx.x;
  ((ushort4*)xrow)[t] = ((const ushort4*)(xln + (size_t)row*D))[t];
  __syncthreads();
  int h = t >> 4, sg = t & 15;
  const u16* xp = xrow + sg*64;
  const float* wpg = wg + (size_t)h*D + sg*64;
  const float* wpa = DUAL ? (wa + (size_t)h*D + sg*64) : nullptr;
  float accg = 0.f, acca = 0.f;
  #pragma unroll
  for(int c = 0; c < 64; ++c){
    float xv = bf2f(xp[c]);
    accg += xv * wpg[c];
    if constexpr (DUAL) acca += xv * wpa[c];
  }
  for(int off = 1; off < 16; off <<= 1){
    accg += __shfl_xor(accg, off);
    if constexpr (DUAL) acca += __shfl_xor(acca, off);
  }
  if(sg == 0){
    int b = row >> 10, s = row & 1023;
    size_t oi = ((size_t)(b*H + h) << 10) + s;
    float r = accg + bg[h];
    outg[oi] = 1.f/(1.f + __expf(-r));
    if constexpr (DUAL) outa[oi] = acca;
  }
}

// ---------------------------------------------------------------- GEMM, BM=64, 2-phase dbuf LDS
// MODE 0: fused qkv (BN=128, N=3072, q pre-scaled 0.125, v transposed out)
// MODE 1: bf16 transposed out (vt);  MODE 2: f32 + resid
template<int MODE, int BN>
__global__ __launch_bounds__(256) void gemm_t(const u16* __restrict__ A,
    const u16* __restrict__ W0, const u16* __restrict__ W1, const u16* __restrict__ W2,
    const float* __restrict__ b0f, const float* __restrict__ b1f, const float* __restrict__ b2f,
    void* __restrict__ o0, void* __restrict__ o1, void* __restrict__ o2,
    const float* __restrict__ resid){
  constexpr int K = 1024;
  constexpr int RN = BN/32;
  constexpr int NBX = (MODE == 0) ? (3072/BN) : (1024/BN);
  constexpr int TOTAL = NBX*32;
  constexpr int CPX = TOTAL/8;
  __shared__ alignas(16) u16 As[2][64*32];
  __shared__ alignas(16) u16 Bs[2][BN*32];
  int bid = blockIdx.x + NBX*blockIdx.y;
  int vid = (bid & 7)*CPX + (bid >> 3);
  int bx = vid % NBX, by = vid / NBX;
  int m0 = by*64, n0g = bx*BN;
  const u16* W; const float* bias; int mat, n0;
  if constexpr (MODE == 0){
    mat = n0g >> 10; n0 = n0g & 1023;
    W = (mat == 0) ? W0 : (mat == 1) ? W1 : W2;
    bias = (mat == 0) ? b0f : (mat == 1) ? b1f : b2f;
  } else { mat = 0; n0 = n0g; W = W0; bias = b0f; }
  int t = threadIdx.x, w = t >> 6, lane = t & 63, g = lane >> 4, l15 = lane & 15;
  int r0 = (w >> 1)*32, c0 = (w & 1)*(BN/2);
  f32x4 acc[2][RN] = {};
  int schk = (lane & 3)*8;
  const u16* Ag = A + (size_t)(m0 + (t >> 2))*K + schk;
  const u16* Wg = W + (size_t)(n0 + (t >> 2))*K + schk;
  const u16* Wg2 = (BN == 128) ? (W + (size_t)(n0 + 64 + (t >> 2))*K + schk) : nullptr;
  auto STAGE = [&](int kt, int buf){
    glds16(Ag + kt*32, &As[buf][w*512]);
    glds16(Wg + kt*32, &Bs[buf][w*512]);
    if constexpr (BN == 128) glds16(Wg2 + kt*32, &Bs[buf][2048 + w*512]);
  };
  STAGE(0, 0);
  __syncthreads();
  int cur = 0;
  for(int kt = 0; kt < K/32; ++kt){
    if(kt + 1 < K/32) STAGE(kt + 1, cur ^ 1);
    bf16x8 af[2], bfr[RN];
    #pragma unroll
    for(int m = 0; m < 2; ++m) af[m] = *(const bf16x8*)&As[cur][(r0 + m*16 + l15)*32 + g*8];
    #pragma unroll
    for(int n = 0; n < RN; ++n) bfr[n] = *(const bf16x8*)&Bs[cur][(c0 + n*16 + l15)*32 + g*8];
    #pragma unroll
    for(int m = 0; m < 2; ++m)
      #pragma unroll
      for(int n = 0; n < RN; ++n)
        acc[m][n] = __builtin_amdgcn_mfma_f32_16x16x32_bf16(af[m], bfr[n], acc[m][n], 0, 0, 0);
    __syncthreads();
    cur ^= 1;
  }
  #pragma unroll
  for(int m = 0; m < 2; ++m){
    #pragma unroll
    for(int n = 0; n < RN; ++n){
      int ng = n0 + c0 + n*16 + l15;
      float bv = bias ? bias[ng] : 0.f;
      #pragma unroll
      for(int i = 0; i < 4; ++i){
        int mg = m0 + r0 + m*16 + g*4 + i;
        float v = acc[m][n][i] + bv;
        if constexpr (MODE == 0){
          if(mat == 0) v *= 0.125f;      // fold DK^-0.5 into Q
          if(mat < 2){
            u16* o = (mat == 0) ? (u16*)o0 : (u16*)o1;
            o[(size_t)mg*D + ng] = f2bf(v);
          } else {
            int b = mg >> 10, s = mg & 1023;
            ((u16*)o2)[((size_t)(b*D + ng))*S + s] = f2bf(v);
          }
        } else if constexpr (MODE == 1){
          int b = mg >> 10, s = mg & 1023;
          ((u16*)o0)[((size_t)(b*D + ng))*S + s] = f2bf(v);
        } else {
          ((float*)o0)[(size_t)mg*1024 + ng] = resid[(size_t)mg*1024 + ng] + v;
        }
      }
    }
  }
}

// ---------------------------------------------------------------- fused attention v3
// 4 waves per block ALL on one (b,h,qt); wave w takes key-chunks kc = w, w+4, ... (KBLK=64)
// online-softmax partials merged in LDS; XCD-chunked swizzle for K/V L2 locality
__device__ __forceinline__ bf16x8 repack8(const float* s, int g, int l15){
  u32 L0 = pack2(s[0], s[1]), L1 = pack2(s[2], s[3]);
  u32 H0 = pack2(s[4], s[5]), H1 = pack2(s[6], s[7]);
  int base = ((g & 1)*2)*16 + l15;
  u32 a0 = (u32)__shfl((int)L0, base),    a1 = (u32)__shfl((int)L1, base);
  u32 b0 = (u32)__shfl((int)L0, base+16), b1 = (u32)__shfl((int)L1, base+16);
  u32 c0 = (u32)__shfl((int)H0, base),    c1 = (u32)__shfl((int)H1, base);
  u32 d0 = (u32)__shfl((int)H0, base+16), d1 = (u32)__shfl((int)H1, base+16);
  bool hi = g >= 2;
  union { u32 wd[4]; bf16x8 v; } pu;
  pu.wd[0] = hi ? c0 : a0;
  pu.wd[1] = hi ? c1 : a1;
  pu.wd[2] = hi ? d0 : b0;
  pu.wd[3] = hi ? d1 : b1;
  return pu.v;
}

template<int MODE>   // 0: SDPA self; 1: SDPA cross; 2: pool self
__global__ __launch_bounds__(256) void attn3_kernel(const u16* __restrict__ Q,
    const u16* __restrict__ Kb, const u16* __restrict__ Vt,
    const float* __restrict__ aprojT, const int* __restrict__ segd,
    const float* __restrict__ gateT, u16* __restrict__ out){
  __shared__ int segL[1024];
  __shared__ float apL[1024];
  __shared__ float mbuf[4][16], lbuf[4][16];
  __shared__ f32x4 obuf[3][4][64];
  __shared__ u16 ot[16][72];
  int bid = blockIdx.x + 64*blockIdx.y;          // grid (64, 32) = 2048
  int vid = (bid & 7)*256 + (bid >> 3);          // XCD-chunked, bijective (2048%8==0)
  int qt = vid & 63, bh = vid >> 6;
  int b = bh >> 4, h = bh & 15;
  int t = threadIdx.x, w = t >> 6, lane = t & 63, g = lane >> 4, l15 = lane & 15;
  { int4 v = ((const int4*)(segd + b*S))[t]; *(int4*)&segL[t*4] = v; }
  if constexpr (MODE == 2){
    float4 v = ((const float4*)(aprojT + ((size_t)bh << 10)))[t];
    *(float4*)&apL[t*4] = v;
  }
  __syncthreads();
  int q = qt*16 + l15;
  float hs = exp2f(-(float)(h + 1) * 0.5f);
  int sdq = segL[q];
  int seg_q = sdq >> 2, mq = sdq & 1;
  bf16x8 qf0 = {}, qf1 = {};
  if constexpr (MODE != 2){
    const u16* qp = Q + ((size_t)(b*S + q))*D + h*DK + g*8;
    qf0 = *(const bf16x8*)qp;
    qf1 = *(const bf16x8*)(qp + 32);
  }
  f32x4 oacc[4] = {};
  float mrun = NEGF, lsum = 0.f;
  int nc = (qt + 4) >> 2;
  const u16* Kbase = Kb + ((size_t)b*S)*D + h*DK + g*8;
  const u16* Vbase = Vt + ((size_t)(bh*DK + l15))*S;

  auto LOADK = [&](bf16x8 (&kb)[8], int kc){
    if constexpr (MODE != 2){
      const u16* p = Kbase + (size_t)(kc*64)*D;
      #pragma unroll
      for(int r = 0; r < 4; ++r){
        const u16* pr = p + (size_t)(r*16 + l15)*D;
        kb[r*2]   = *(const bf16x8*)pr;
        kb[r*2+1] = *(const bf16x8*)(pr + 32);
      }
    }
  };
  auto STEP = [&](bf16x8 (&kb)[8], int kc){
    int k0 = kc*64;
    bf16x8 vr[8];
    #pragma unroll
    for(int c = 0; c < 4; ++c){
      const u16* vp = Vbase + (size_t)(c*16)*S + k0 + g*8;
      vr[c*2]   = *(const bf16x8*)vp;
      vr[c*2+1] = *(const bf16x8*)(vp + 32);
    }
    float sv[16];
    if constexpr (MODE != 2){
      __builtin_amdgcn_s_setprio(1);
      #pragma unroll
      for(int r = 0; r < 4; ++r){
        f32x4 sa = {};
        sa = __builtin_amdgcn_mfma_f32_16x16x32_bf16(kb[r*2],   qf0, sa, 0, 0, 0);
        sa = __builtin_amdgcn_mfma_f32_16x16x32_bf16(kb[r*2+1], qf1, sa, 0, 0, 0);
        #pragma unroll
        for(int i = 0; i < 4; ++i) sv[r*4+i] = sa[i];
      }
      __builtin_amdgcn_s_setprio(0);
    } else {
      #pragma unroll
      for(int r = 0; r < 4; ++r){
        float4 a4 = *(const float4*)&apL[k0 + r*16 + g*4];
        sv[r*4+0] = a4.x; sv[r*4+1] = a4.y; sv[r*4+2] = a4.z; sv[r*4+3] = a4.w;
      }
    }
    #pragma unroll
    for(int r = 0; r < 4; ++r){
      int4 sd4 = *(const int4*)&segL[k0 + r*16 + g*4];
      int sds[4] = { sd4.x, sd4.y, sd4.z, sd4.w };
      #pragma unroll
      for(int i = 0; i < 4; ++i){
        int key = k0 + r*16 + g*4 + i;
        int sdk = sds[i];
        bool ok; float val;
        if constexpr (MODE == 1){
          ok = (key < q && (sdk & 2)) || (key == q);
          val = (float)((sdk >> 2) - seg_q);
        } else {
          ok = (key < q && ((sdk >> 2) == seg_q) && (sdk & mq & 1)) || (key == q);
          val = (float)(key - q);
        }
        sv[r*4+i] = ok ? sv[r*4+i] + val*hs : NEGF;
      }
    }
    float cm = sv[0];
    #pragma unroll
    for(int i = 1; i < 16; ++i) cm = fmaxf(cm, sv[i]);
    cm = fmaxf(cm, __shfl_xor(cm, 16));
    cm = fmaxf(cm, __shfl_xor(cm, 32));
    float mnew = fmaxf(mrun, cm);
    float fac = __expf(mrun - mnew);
    float ps = 0.f;
    #pragma unroll
    for(int i = 0; i < 16; ++i){ sv[i] = __expf(sv[i] - mnew); ps += sv[i]; }
    ps += __shfl_xor(ps, 16);
    ps += __shfl_xor(ps, 32);
    lsum = lsum * fac + ps;
    mrun = mnew;
    #pragma unroll
    for(int c = 0; c < 4; ++c)
      #pragma unroll
      for(int i = 0; i < 4; ++i) oacc[c][i] *= fac;
    __builtin_amdgcn_s_setprio(1);
    #pragma unroll
    for(int ks = 0; ks < 2; ++ks){
      bf16x8 pf = repack8(&sv[ks*8], g, l15);
      #pragma unroll
      for(int c = 0; c < 4; ++c)
        oacc[c] = __builtin_amdgcn_mfma_f32_16x16x32_bf16(vr[c*2+ks], pf, oacc[c], 0, 0, 0);
    }
    __builtin_amdgcn_s_setprio(0);
  };

  bf16x8 kbufA[8], kbufB[8];
  int kc = w;
  bool useA = true;
  if(kc < nc) LOADK(kbufA, kc);
  while(kc < nc){
    if(useA){
      if(kc + 4 < nc) LOADK(kbufB, kc + 4);
      STEP(kbufA, kc);
    } else {
      if(kc + 4 < nc) LOADK(kbufA, kc + 4);
      STEP(kbufB, kc);
    }
    useA = !useA;
    kc += 4;
  }

  // merge 4 partials
  if(w > 0){
    #pragma unroll
    for(int c = 0; c < 4; ++c) obuf[w-1][c][lane] = oacc[c];
  }
  if(g == 0){ mbuf[w][l15] = mrun; lbuf[w][l15] = lsum; }
  __syncthreads();
  if(w == 0){
    float m1 = mbuf[1][l15], m2 = mbuf[2][l15], m3 = mbuf[3][l15];
    float M = fmaxf(fmaxf(mrun, m1), fmaxf(m2, m3));
    float f0 = __expf(mrun - M), f1 = __expf(m1 - M);
    float f2 = __expf(m2 - M), f3 = __expf(m3 - M);
    float L = lsum*f0 + lbuf[1][l15]*f1 + lbuf[2][l15]*f2 + lbuf[3][l15]*f3;
    float scale = (1.f / L) * gateT[((size_t)bh << 10) + q];
    #pragma unroll
    for(int c = 0; c < 4; ++c){
      f32x4 o = oacc[c]*f0 + obuf[0][c][lane]*f1 + obuf[1][c][lane]*f2 + obuf[2][c][lane]*f3;
      #pragma unroll
      for(int i = 0; i < 4; i += 2){
        u32 p = pack2(o[i]*scale, o[i+1]*scale);
        *(u32*)&ot[l15][c*16 + g*4 + i] = p;
      }
    }
    int r = lane >> 2, c4 = lane & 3;
    uint4 v0 = *(uint4*)&ot[r][c4*16];
    uint4 v1 = *(uint4*)&ot[r][c4*16 + 8];
    u16* op = out + ((size_t)(b*S + qt*16 + r))*D + h*DK + c4*16;
    *(uint4*)op = v0;
    *(uint4*)(op + 8) = v1;
  }
}

} // namespace

extern "C" void kernel_launch(void* const* d_in, const int* in_sizes, int n_in,
                              void* d_out, int out_size, void* d_ws, size_t ws_size,
                              hipStream_t stream){
  (void)in_sizes; (void)n_in; (void)out_size; (void)ws_size;
  const float* states = (const float*)d_in[0];
  const int*   ids    = (const int*)d_in[1];
  float* xout = (float*)d_out;

  char* w = (char*)d_ws;
  u16* wbf[10];
  for(int i = 0; i < 10; ++i){ wbf[i] = (u16*)w; w += (size_t)1024*1024*2; }
  u16* xln  = (u16*)w; w += (size_t)2048*1024*2;
  u16* qb   = (u16*)w; w += (size_t)2048*1024*2;
  u16* kb   = (u16*)w; w += (size_t)2048*1024*2;
  u16* vt   = (u16*)w; w += (size_t)2048*1024*2;
  u16* attn = (u16*)w; w += (size_t)2048*1024*2;
  float* gateT  = (float*)w; w += (size_t)2048*16*4;
  float* aprojT = (float*)w; w += (size_t)2048*16*4;
  int* segd = (int*)w;

  const int widx[10] = {4, 6, 8, 12, 17, 21, 25, 27, 29, 33};
  CvtArgs ca;
  for(int i = 0; i < 10; ++i){ ca.src[i] = (const float*)d_in[widx[i]]; ca.dst[i] = wbf[i]; }
  cvt_kernel<<<dim3(512, 10), dim3(256), 0, stream>>>(ca);
  seg_kernel<<<dim3(2), dim3(1024), 0, stream>>>(ids, segd);

  dim3 b256(256), g2048(2048);
  dim3 gqkv(24, 32), ggen(16, 32), gattn(64, 32);

  // ---- layer 0: SDPA, self bias
  ln_kernel<<<g2048, b256, 0, stream>>>(states, (const float*)d_in[2], (const float*)d_in[3], xln);
  gemm_t<0,128><<<gqkv, b256, 0, stream>>>(xln, wbf[0], wbf[1], wbf[2],
      (const float*)d_in[5], (const float*)d_in[7], (const float*)d_in[9], qb, kb, vt, nullptr);
  headproj_kernel<false><<<g2048, b256, 0, stream>>>(xln, (const float*)d_in[10], (const float*)d_in[11], gateT, nullptr, nullptr);
  attn3_kernel<0><<<gattn, b256, 0, stream>>>(qb, kb, vt, nullptr, segd, gateT, attn);
  gemm_t<2,64><<<ggen, b256, 0, stream>>>(attn, wbf[3], nullptr, nullptr,
      (const float*)d_in[13], nullptr, nullptr, xout, nullptr, nullptr, states);

  // ---- layer 1: pool, self bias
  ln_kernel<<<g2048, b256, 0, stream>>>(xout, (const float*)d_in[14], (const float*)d_in[15], xln);
  gemm_t<1,64><<<ggen, b256, 0, stream>>>(xln, wbf[4], nullptr, nullptr,
      (const float*)d_in[18], nullptr, nullptr, vt, nullptr, nullptr, nullptr);
  headproj_kernel<true><<<g2048, b256, 0, stream>>>(xln, (const float*)d_in[19], (const float*)d_in[20], gateT,
      (const float*)d_in[16], aprojT);
  attn3_kernel<2><<<gattn, b256, 0, stream>>>(nullptr, nullptr, vt, aprojT, segd, gateT, attn);
  gemm_t<2,64><<<ggen, b256, 0, stream>>>(attn, wbf[5], nullptr, nullptr,
      (const float*)d_in[22], nullptr, nullptr, xout, nullptr, nullptr, xout);

  // ---- layer 2: SDPA, cross bias
  ln_kernel<<<g2048, b256, 0, stream>>>(xout, (const float*)d_in[23], (const float*)d_in[24], xln);
  gemm_t<0,128><<<gqkv, b256, 0, stream>>>(xln, wbf[6], wbf[7], wbf[8],
      (const float*)d_in[26], (const float*)d_in[28], (const float*)d_in[30], qb, kb, vt, nullptr);
  headproj_kernel<false><<<g2048, b256, 0, stream>>>(xln, (const float*)d_in[31], (const float*)d_in[32], gateT, nullptr, nullptr);
  attn3_kernel<1><<<gattn, b256, 0, stream>>>(qb, kb, vt, nullptr, segd, gateT, attn);
  gemm_t<2,64><<<ggen, b256, 0, stream>>>(attn, wbf[9], nullptr, nullptr,
      (const float*)d_in[34], nullptr, nullptr, xout, nullptr, nullptr, xout);
}